// Round 10
// baseline (127.971 us; speedup 1.0000x reference)
//
#include <hip/hip_runtime.h>
#include <hip/hip_fp16.h>

#define NN 1024
#define HH 128
#define QR 2
#define ITR 8       // rows per i-tile
#define JS 8        // j-splits
#define JT (NN/JS)  // 128 j per block
#define TPA 512

typedef _Float16 f16x2_t __attribute__((ext_vector_type(2)));

__device__ __forceinline__ float dot2(__half2 a, __half2 b, float c) {
#if __has_builtin(__builtin_amdgcn_fdot2)
  return __builtin_amdgcn_fdot2(__builtin_bit_cast(f16x2_t, a),
                                __builtin_bit_cast(f16x2_t, b), c, false);
#else
  return fmaf(__low2float(a), __low2float(b),
              fmaf(__high2float(a), __high2float(b), c));
#endif
}

// packed-f16 relu: max(a, 0) per half (v_pk_max_f16); ROCm lacks __hmax2
__device__ __forceinline__ __half2 relu2(__half2 a) {
#if __has_builtin(__builtin_elementwise_max)
  f16x2_t v = __builtin_bit_cast(f16x2_t, a);
  f16x2_t z = {(_Float16)0.f, (_Float16)0.f};
  return __builtin_bit_cast(__half2, __builtin_elementwise_max(v, z));
#else
  unsigned int av = __builtin_bit_cast(unsigned int, a);
  unsigned int rv;
  asm("v_pk_max_f16 %0, %1, 0" : "=v"(rv) : "v"(av));
  return __builtin_bit_cast(__half2, rv);
#endif
}

__device__ __forceinline__ float2 wmax2(float2 v) {
#pragma unroll
  for (int off = 1; off < 64; off <<= 1) {
    v.x = fmaxf(v.x, __shfl_xor(v.x, off));
    v.y = fmaxf(v.y, __shfl_xor(v.y, off));
  }
  return v;
}
__device__ __forceinline__ float2 wsum2(float2 v) {
#pragma unroll
  for (int off = 1; off < 64; off <<= 1) {
    v.x += __shfl_xor(v.x, off);
    v.y += __shfl_xor(v.y, off);
  }
  return v;
}

// ---------------- prep: W transposes + edge params (f32 + packed f16) + c0 ----------------
__global__ __launch_bounds__(128)
void prep_kernel(const float* __restrict__ Wq, const float* __restrict__ Wk,
                 const float* __restrict__ Wv, const float* __restrict__ We1,
                 const float* __restrict__ be1, const float* __restrict__ We2,
                 const float* __restrict__ be2, const float* __restrict__ Wc,
                 const float* __restrict__ bc,
                 float* __restrict__ WqT, float* __restrict__ WkT,
                 float* __restrict__ WvT, float* __restrict__ epack,
                 float* __restrict__ c0,
                 __half2* __restrict__ aB, __half2* __restrict__ bB,
                 __half2* __restrict__ uB) {
  __shared__ float su[HH];
  const int d = blockIdx.x;
  const int o = threadIdx.x;
  WqT[d * HH + o] = Wq[o * HH + d];
  WkT[d * HH + o] = Wk[o * HH + d];
  WvT[d * HH + o] = Wv[o * HH + d];
  if (d == 0) {
    // u[t] = sum_e Wc[e] * We2[e][t]   (fold Wc @ We2)
    float uu = 0.f;
    for (int e = 0; e < HH; ++e) uu = fmaf(Wc[e], We2[e * HH + o], uu);
    su[o] = uu;
    epack[o * 4 + 0] = We1[2 * o];
    epack[o * 4 + 1] = We1[2 * o + 1];
    epack[o * 4 + 2] = be1[o];
    epack[o * 4 + 3] = uu;
    if (o == 0) {
      float s = bc[0];
      for (int e = 0; e < HH; ++e) s = fmaf(Wc[e], be2[e], s);
      c0[0] = s;
    }
    __syncthreads();
    if (o < 64) {  // packed f16 over t-pairs (t = 2o, 2o+1)
      aB[o] = __halves2half2(__float2half(We1[4 * o]), __float2half(We1[4 * o + 2]));
      bB[o] = __halves2half2(__float2half(We1[4 * o + 1]), __float2half(We1[4 * o + 3]));
      uB[o] = __halves2half2(__float2half(su[2 * o]), __float2half(su[2 * o + 1]));
    }
  }
}

// ---------------- qkv: q f16 (scaled), k in k8[c][j][8] f16 groups, v f16 ----------------
__global__ __launch_bounds__(128)
void qkv_kernel(const float* __restrict__ hin,
                const float* __restrict__ WqT, const float* __restrict__ WkT,
                const float* __restrict__ WvT,
                const float* __restrict__ bq, const float* __restrict__ bk,
                const float* __restrict__ bv,
                __half* __restrict__ q16, __half* __restrict__ k8,
                __half* __restrict__ v16) {
  __shared__ __align__(16) float hT[HH][QR];
  const int tid = threadIdx.x;   // output feature o
  const int i0 = blockIdx.x * QR;
#pragma unroll
  for (int r = 0; r < QR; ++r) hT[tid][r] = hin[(i0 + r) * HH + tid];
  __syncthreads();
  float qa0 = 0.f, qa1 = 0.f, ka0 = 0.f, ka1 = 0.f, va0 = 0.f, va1 = 0.f;
#pragma unroll 4
  for (int d = 0; d < HH; ++d) {
    float wq = WqT[d * HH + tid];
    float wk = WkT[d * HH + tid];
    float wv = WvT[d * HH + tid];
    float2 hh = *(const float2*)&hT[d][0];
    qa0 = fmaf(hh.x, wq, qa0); qa1 = fmaf(hh.y, wq, qa1);
    ka0 = fmaf(hh.x, wk, ka0); ka1 = fmaf(hh.y, wk, ka1);
    va0 = fmaf(hh.x, wv, va0); va1 = fmaf(hh.y, wv, va1);
  }
  const float scale = 0.08838834764831845f;  // 1/sqrt(128), folded into q
  float bqv = bq[tid], bkv = bk[tid], bvv = bv[tid];
  q16[(i0 + 0) * HH + tid] = __float2half((qa0 + bqv) * scale);
  q16[(i0 + 1) * HH + tid] = __float2half((qa1 + bqv) * scale);
  // k8: feature group c = o/8, slot o%8 -> 16B per (c, j), coalesced read side
  const int c = tid >> 3, slot = tid & 7;
  k8[(size_t)((c * NN + i0 + 0) << 3) + slot] = __float2half(ka0 + bkv);
  k8[(size_t)((c * NN + i0 + 1) << 3) + slot] = __float2half(ka1 + bkv);
  v16[(i0 + 0) * HH + tid] = __float2half(va0 + bvv);
  v16[(i0 + 1) * HH + tid] = __float2half(va1 + bvv);
}

// ---------------- stage A: partial attention + edge over one (i-tile, j-split) ----------------
// grid 1024 = 128 i-tiles x 8 j-splits, 512 threads. 4 blocks/CU (100% wave cap).
__global__ __launch_bounds__(TPA, 8)
void stageA_kernel(const __half* __restrict__ q16, const __half* __restrict__ k8,
                   const __half* __restrict__ v16, const float* __restrict__ x,
                   const float* __restrict__ epack,
                   const __half2* __restrict__ aB, const __half2* __restrict__ bB,
                   const __half2* __restrict__ uB, const float* __restrict__ c0p,
                   float2* __restrict__ ws_sm, float2* __restrict__ ws_cxy,
                   float* __restrict__ ws_pv) {
  __shared__ __align__(16) float sp[JT][ITR];     // 4KB  exp(s-m_loc), [j][r]
  __shared__ __align__(16) float sred[ITR][8][HH]; // 32KB PV chunk partials [r][cc][f]
  __shared__ __half2 stab[ITR][64];                // 2KB
  __shared__ float2 redm[8], reds[8], redx[8], redy[8];

  const int tid = threadIdx.x;
  const int lane = tid & 63;
  const int wid = tid >> 6;       // 0..7
  const int b = blockIdx.x;
  const int it = b >> 3, js = b & 7;
  const int i0 = it * ITR;
  const int jb = js * JT;

  // ---- phase 0: stab[r][tp] (512 threads exactly cover 8r x 64tp)
  {
    const int r = tid & 7, tp = tid >> 3;
    const float4 ea = ((const float4*)epack)[2 * tp];
    const float4 eb = ((const float4*)epack)[2 * tp + 1];
    float xrx = x[(i0 + r) * 2 + 0], xry = x[(i0 + r) * 2 + 1];
    stab[r][tp] = __halves2half2(
        __float2half(fmaf(ea.x, xrx, fmaf(ea.y, xry, ea.z))),
        __float2half(fmaf(eb.x, xrx, fmaf(eb.y, xry, eb.z))));
  }

  const int jl = tid & (JT - 1);  // 0..127
  const int rg = tid >> 7;        // 0..3 (wave-uniform): rows 2rg, 2rg+1
  const int jg = jb + jl;

  // ---- scores: coalesced k8 dwordx4, q via wave-uniform s_load
  const __half2* q0p = (const __half2*)(q16 + (size_t)(i0 + 2 * rg) * HH);
  const __half2* q1p = (const __half2*)(q16 + (size_t)(i0 + 2 * rg + 1) * HH);
  const float4* k84 = (const float4*)k8;
  float s0 = 0.f, s1 = 0.f;
#pragma unroll
  for (int c = 0; c < 16; ++c) {
    float4 ka = k84[c * NN + jg];
    __half2 a0 = __builtin_bit_cast(__half2, ka.x);
    __half2 a1 = __builtin_bit_cast(__half2, ka.y);
    __half2 a2 = __builtin_bit_cast(__half2, ka.z);
    __half2 a3 = __builtin_bit_cast(__half2, ka.w);
    __half2 qa0 = q0p[4 * c + 0], qa1 = q0p[4 * c + 1];
    __half2 qa2 = q0p[4 * c + 2], qa3 = q0p[4 * c + 3];
    __half2 qb0 = q1p[4 * c + 0], qb1 = q1p[4 * c + 1];
    __half2 qb2 = q1p[4 * c + 2], qb3 = q1p[4 * c + 3];
    s0 = dot2(a0, qa0, s0); s0 = dot2(a1, qa1, s0);
    s0 = dot2(a2, qa2, s0); s0 = dot2(a3, qa3, s0);
    s1 = dot2(a0, qb0, s1); s1 = dot2(a1, qb1, s1);
    s1 = dot2(a2, qb2, s1); s1 = dot2(a3, qb3, s1);
  }

  // ---- local (per-block) row max
  float2 mv = wmax2(make_float2(s0, s1));
  if (lane == 0) redm[wid] = mv;
  __syncthreads();   // #1: redm + stab
  float2 ma = redm[2 * rg], mb = redm[2 * rg + 1];
  float mmx = fmaxf(ma.x, mb.x), mmy = fmaxf(ma.y, mb.y);
  float e0 = __expf(s0 - mmx), e1 = __expf(s1 - mmy);
  sp[jl][2 * rg] = e0; sp[jl][2 * rg + 1] = e1;
  float2 sv = wsum2(make_float2(e0, e1));
  if (lane == 0) reds[wid] = sv;

  // ---- edge loop (register-resident e0/e1; stab from LDS)
  float2 xj = *(const float2*)&x[2 * jg];
  __half2 xjx2 = __float2half2_rn(xj.x);
  __half2 xjy2 = __float2half2_rn(xj.y);
  float wa0 = 0.f, wa1 = 0.f;
#pragma unroll 8
  for (int tp = 0; tp < 64; ++tp) {
    __half2 a2 = aB[tp], b2 = bB[tp], u2 = uB[tp];   // uniform -> s_load
    __half2 w2h = __hfma2(a2, xjx2, __hmul2(b2, xjy2));
    wa0 = dot2(u2, relu2(__hsub2(stab[2 * rg][tp], w2h)), wa0);
    wa1 = dot2(u2, relu2(__hsub2(stab[2 * rg + 1][tp], w2h)), wa1);
  }
  const float c0v = c0p[0];
  float cw0 = e0 * (wa0 + c0v);
  float cw1 = e1 * (wa1 + c0v);
  float xi0x = x[(i0 + 2 * rg) * 2 + 0],     xi0y = x[(i0 + 2 * rg) * 2 + 1];
  float xi1x = x[(i0 + 2 * rg + 1) * 2 + 0], xi1y = x[(i0 + 2 * rg + 1) * 2 + 1];
  float2 rx = wsum2(make_float2(cw0 * (xi0x - xj.x), cw1 * (xi1x - xj.x)));
  float2 ry = wsum2(make_float2(cw0 * (xi0y - xj.y), cw1 * (xi1y - xj.y)));
  if (lane == 0) { redx[wid] = rx; redy[wid] = ry; }
  __syncthreads();   // #2: sp + reds + redx/redy

  // ---- per-row scalars -> ws (sum, m) and raw coord partials
  if (tid < ITR) {
    const int r = tid, g = r >> 1;
    float2 sa = reds[2 * g], sb = reds[2 * g + 1];
    float2 m2a = redm[2 * g], m2b = redm[2 * g + 1];
    float2 xa = redx[2 * g], xb = redx[2 * g + 1];
    float2 ya = redy[2 * g], yb = redy[2 * g + 1];
    float sum, mrow, cx, cy;
    if (r & 1) { sum = sa.y + sb.y; mrow = fmaxf(m2a.y, m2b.y); cx = xa.y + xb.y; cy = ya.y + yb.y; }
    else       { sum = sa.x + sb.x; mrow = fmaxf(m2a.x, m2b.x); cx = xa.x + xb.x; cy = ya.x + yb.x; }
    ws_sm[b * ITR + r]  = make_float2(sum, mrow);
    ws_cxy[b * ITR + r] = make_float2(cx, cy);
  }

  // ---- PV partial: thread = (feature pair fp, chunk cc of 16 j), f16 v
  {
    const int fp = tid & 63;       // features 2fp, 2fp+1
    const int cc = tid >> 6;       // 0..7 (wave-uniform)
    const __half2* v2 = (const __half2*)v16;
    float accA[8], accB[8];
#pragma unroll
    for (int r = 0; r < 8; ++r) { accA[r] = 0.f; accB[r] = 0.f; }
#pragma unroll 4
    for (int jj = 0; jj < 16; ++jj) {
      const int jl2 = cc * 16 + jj;
      __half2 vv = v2[(size_t)(jb + jl2) * 64 + fp];   // coalesced dword
      float vx = __low2float(vv), vy = __high2float(vv);
      const float4* pr = (const float4*)&sp[jl2][0];   // uniform b128 broadcast
      float4 pa = pr[0], pb = pr[1];
      accA[0] = fmaf(pa.x, vx, accA[0]); accB[0] = fmaf(pa.x, vy, accB[0]);
      accA[1] = fmaf(pa.y, vx, accA[1]); accB[1] = fmaf(pa.y, vy, accB[1]);
      accA[2] = fmaf(pa.z, vx, accA[2]); accB[2] = fmaf(pa.z, vy, accB[2]);
      accA[3] = fmaf(pa.w, vx, accA[3]); accB[3] = fmaf(pa.w, vy, accB[3]);
      accA[4] = fmaf(pb.x, vx, accA[4]); accB[4] = fmaf(pb.x, vy, accB[4]);
      accA[5] = fmaf(pb.y, vx, accA[5]); accB[5] = fmaf(pb.y, vy, accB[5]);
      accA[6] = fmaf(pb.z, vx, accA[6]); accB[6] = fmaf(pb.z, vy, accB[6]);
      accA[7] = fmaf(pb.w, vx, accA[7]); accB[7] = fmaf(pb.w, vy, accB[7]);
    }
#pragma unroll
    for (int r = 0; r < 8; ++r)
      *(float2*)&sred[r][cc][2 * fp] = make_float2(accA[r], accB[r]);  // stride-1, conflict-free
  }
  __syncthreads();   // #3: sred ready

  // ---- reduce 8 chunks -> ws_pv [b][r][f]
  {
    const int f = tid & 127, rp = tid >> 7;  // rows 2rp, 2rp+1
    float a0 = 0.f, a1 = 0.f;
#pragma unroll
    for (int c2 = 0; c2 < 8; ++c2) {
      a0 += sred[2 * rp][c2][f];
      a1 += sred[2 * rp + 1][c2][f];
    }
    ws_pv[(size_t)(b * ITR + 2 * rp) * HH + f]     = a0;
    ws_pv[(size_t)(b * ITR + 2 * rp + 1) * HH + f] = a1;
  }
}

// ---------------- stage B: merge 8 j-split partials (flash rescale) ----------------
__global__ __launch_bounds__(1024)
void stageB_kernel(const float2* __restrict__ ws_sm, const float2* __restrict__ ws_cxy,
                   const float* __restrict__ ws_pv, const float* __restrict__ hin,
                   const float* __restrict__ x,
                   float* __restrict__ out_h, float* __restrict__ out_x) {
  const int it = blockIdx.x;
  const int tid = threadIdx.x;
  const int f = tid & 127, r = tid >> 7;
  const int i0 = it * ITR;

  float m[JS], s[JS];
  float M = -1e30f;
#pragma unroll
  for (int js = 0; js < JS; ++js) {
    float2 sm = ws_sm[(it * JS + js) * ITR + r];
    s[js] = sm.x; m[js] = sm.y; M = fmaxf(M, sm.y);
  }
  float sc[JS], S = 0.f;
#pragma unroll
  for (int js = 0; js < JS; ++js) { sc[js] = __expf(m[js] - M); S = fmaf(sc[js], s[js], S); }
  const float inv = 1.f / S;

  float acc = 0.f;
#pragma unroll
  for (int js = 0; js < JS; ++js)
    acc = fmaf(sc[js], ws_pv[(size_t)((it * JS + js) * ITR + r) * HH + f], acc);
  out_h[(i0 + r) * HH + f] = hin[(i0 + r) * HH + f] + acc * inv;

  if (tid < ITR) {
    const int rr = tid;
    float mm2[JS], ss2[JS];
    float MM = -1e30f;
#pragma unroll
    for (int js = 0; js < JS; ++js) {
      float2 sm = ws_sm[(it * JS + js) * ITR + rr];
      ss2[js] = sm.x; mm2[js] = sm.y; MM = fmaxf(MM, sm.y);
    }
    float SS = 0.f, cx = 0.f, cy = 0.f;
#pragma unroll
    for (int js = 0; js < JS; ++js) {
      float scj = __expf(mm2[js] - MM);
      SS = fmaf(scj, ss2[js], SS);
      float2 c2 = ws_cxy[(it * JS + js) * ITR + rr];
      cx = fmaf(scj, c2.x, cx);
      cy = fmaf(scj, c2.y, cy);
    }
    float invr = 1.f / SS;
    out_x[(i0 + rr) * 2 + 0] = x[(i0 + rr) * 2 + 0] + cx * invr;
    out_x[(i0 + rr) * 2 + 1] = x[(i0 + rr) * 2 + 1] + cy * invr;
  }
}

extern "C" void kernel_launch(void* const* d_in, const int* in_sizes, int n_in,
                              void* d_out, int out_size, void* d_ws, size_t ws_size,
                              hipStream_t stream) {
  (void)in_sizes; (void)n_in; (void)out_size; (void)ws_size;
  const float* h   = (const float*)d_in[0];
  const float* x   = (const float*)d_in[1];
  // d_in[2] = batch (all zeros, unused)
  const float* Wq  = (const float*)d_in[3];
  const float* bq  = (const float*)d_in[4];
  const float* Wk  = (const float*)d_in[5];
  const float* bk  = (const float*)d_in[6];
  const float* Wv  = (const float*)d_in[7];
  const float* bv  = (const float*)d_in[8];
  const float* We1 = (const float*)d_in[9];
  const float* be1 = (const float*)d_in[10];
  const float* We2 = (const float*)d_in[11];
  const float* be2 = (const float*)d_in[12];
  const float* Wc  = (const float*)d_in[13];
  const float* bc  = (const float*)d_in[14];

  float* ws   = (float*)d_ws;
  float* WqT  = ws;                   // 16384 f32
  float* WkT  = WqT + HH * HH;
  float* WvT  = WkT + HH * HH;
  float* ep   = WvT + HH * HH;        // 512 f32
  float* c0   = ep + 4 * HH;          // 8 (padded)
  __half* q16 = (__half*)(c0 + 8);       // N*H halves (scaled q), row-major
  __half* k8  = q16 + NN * HH;           // N*H halves, [c][j][8] groups
  __half* v16 = k8 + NN * HH;            // N*H halves, row-major
  __half2* aB = (__half2*)(v16 + NN * HH);  // 64 half2
  __half2* bB = aB + 64;
  __half2* uB = bB + 64;
  float2* ws_sm  = (float2*)(uB + 64);      // 1024*8 float2 (sum, m)
  float2* ws_cxy = ws_sm + (128 * JS * ITR);// 1024*8 float2 (cx, cy)
  float*  ws_pv  = (float*)(ws_cxy + (128 * JS * ITR));  // 1024*8*128 f32 (4.2MB)

  float* out_h = (float*)d_out;            // N*H
  float* out_x = out_h + NN * HH;          // N*2

  prep_kernel<<<dim3(HH), dim3(128), 0, stream>>>(
      Wq, Wk, Wv, We1, be1, We2, be2, Wc, bc, WqT, WkT, WvT, ep, c0, aB, bB, uB);
  qkv_kernel<<<dim3(NN / QR), dim3(128), 0, stream>>>(
      h, WqT, WkT, WvT, bq, bk, bv, q16, k8, v16);
  stageA_kernel<<<dim3(128 * JS), dim3(TPA), 0, stream>>>(
      q16, k8, v16, x, ep, aB, bB, uB, c0, ws_sm, ws_cxy, ws_pv);
  stageB_kernel<<<dim3(128), dim3(1024), 0, stream>>>(
      ws_sm, ws_cxy, ws_pv, h, x, out_h, out_x);
}